// Round 6
// baseline (486.882 us; speedup 1.0000x reference)
//
#include <hip/hip_runtime.h>

#define LOG2E 1.4426950408889634f
#define SCALE 0.6830207f   // 2048^(-0.05)

typedef __attribute__((ext_vector_type(8))) _Float16 f16x8;
typedef __attribute__((ext_vector_type(4))) _Float16 f16x4;
typedef __attribute__((ext_vector_type(4))) float f32x4;

// Bare barrier: lockstep hint only (no cross-wave LDS data anywhere), so no
// waitcnt drain needed. Keeps a block's waves on the same tile for L1 reuse.
__device__ __forceinline__ void lockstep() { asm volatile("s_barrier"); }

// ---- prep: W (3x [2048][128] fp32) -> fp16 MFMA B-frag layout ----
// Wf[kc][nt][lane][j] = W[k = kc*32 + (lane>>4)*8 + j][n = nt*16 + (lane&15)]
__global__ __launch_bounds__(256) void prep_wf(const float* __restrict__ Wq,
    const float* __restrict__ Wk, const float* __restrict__ Wv,
    _Float16* __restrict__ Wf) {
  int t = blockIdx.x * 256 + threadIdx.x;   // 0..98303
  int lane = t & 63;
  int nt = (t >> 6) % 24;
  int kc = t / (64 * 24);
  int g = lane >> 4, c = lane & 15;
  int n = nt * 16 + c;
  const float* W = (n < 128) ? Wq : ((n < 256) ? Wk : Wv);
  int nn = n & 127;
  f16x8 o;
#pragma unroll
  for (int j = 0; j < 8; ++j) {
    int k = kc * 32 + g * 8 + j;
    o[j] = (_Float16)W[k * 128 + nn];
  }
  *(f16x8*)(Wf + (size_t)t * 8) = o;
}

// ---- projection: BM=64, LDS-free, barrier-free (lockstep hint only) ----
// wave w owns rows m0 + w*16 + c, all 24 n-tiles; A row-gather, B direct L2.
__global__ __launch_bounds__(256) void proj(const float* __restrict__ x,
    const _Float16* __restrict__ Wf,
    _Float16* __restrict__ qo, _Float16* __restrict__ ko,
    _Float16* __restrict__ vTo) {
  int tid = threadIdx.x;
  int wave = tid >> 6, lane = tid & 63;
  int g = lane >> 4, c = lane & 15;
  int m0 = blockIdx.x * 64;
  const f32x4 fz = {0.f, 0.f, 0.f, 0.f};
  f32x4 acc[24];
#pragma unroll
  for (int q = 0; q < 24; ++q) acc[q] = fz;

  const float* xp = x + (size_t)(m0 + wave * 16 + c) * 2048 + g * 8;

  for (int kb = 0; kb < 64; ++kb) {
    float4 a0 = *(const float4*)(xp + kb * 32);
    float4 a1 = *(const float4*)(xp + kb * 32 + 4);
    f16x8 af;
    af[0] = (_Float16)a0.x; af[1] = (_Float16)a0.y;
    af[2] = (_Float16)a0.z; af[3] = (_Float16)a0.w;
    af[4] = (_Float16)a1.x; af[5] = (_Float16)a1.y;
    af[6] = (_Float16)a1.z; af[7] = (_Float16)a1.w;
#pragma unroll
    for (int nt = 0; nt < 24; ++nt) {
      f16x8 bf = *(const f16x8*)(Wf + ((size_t)(kb * 24 + nt) * 64 + lane) * 8);
      acc[nt] = __builtin_amdgcn_mfma_f32_16x16x32_f16(af, bf, acc[nt], 0, 0, 0);
    }
    lockstep();
  }
  // epilogue: D[row=(lane>>4)*4+i][col=lane&15]
#pragma unroll
  for (int nt = 0; nt < 24; ++nt) {
    int n = nt * 16 + c;
    int mat = n >> 7, col = n & 127;
#pragma unroll
    for (int i = 0; i < 4; ++i) {
      int row = m0 + wave * 16 + g * 4 + i;
      _Float16 hv = (_Float16)acc[nt][i];
      if (mat == 0)      qo[(size_t)row * 128 + col] = hv;
      else if (mat == 1) ko[(size_t)row * 128 + col] = hv;
      else               vTo[(size_t)col * 16384 + row] = hv;
    }
  }
}

// ---- flash attention partials: BQ=128, direct-global K/V gathers, no LDS
//      staging (LDS only for per-wave P round-trip), no sync barriers ----
__global__ __launch_bounds__(256, 2) void attn_part(
    const _Float16* __restrict__ qg, const _Float16* __restrict__ kg,
    const _Float16* __restrict__ vT,
    float* __restrict__ Op, float* __restrict__ Ml) {
  __shared__ __align__(16) _Float16 Ps[4][2][16 * 72]; // [wave][sub][q][kv pad]
  int tid = threadIdx.x;
  int wave = tid >> 6, lane = tid & 63;
  int g = lane >> 4, c = lane & 15;
  int u = blockIdx.x;
  int b = u / 80, t = u % 80;
  int qt, ch;   // qt in 0..31 (128-row Q tiles), chunk of 16 KV-tiles
  if (t < 8)       { qt = t;                 ch = 0; }
  else if (t < 24) { qt = 8  + (t - 8)  / 2; ch = (t - 8)  % 2; }
  else if (t < 48) { qt = 16 + (t - 24) / 3; ch = (t - 24) % 3; }
  else             { qt = 24 + (t - 48) / 4; ch = (t - 48) % 4; }
  int q0 = qt * 128;
  int jbeg = ch * 16, jend = min(jbeg + 16, 2 * qt + 2);
  size_t base = (size_t)b * 4096 * 128;

  // Q as B-frags (resident): qf[sub][kc]
  f16x8 qf[2][4];
#pragma unroll
  for (int s = 0; s < 2; ++s)
#pragma unroll
    for (int kc = 0; kc < 4; ++kc)
      qf[s][kc] = *(const f16x8*)(qg + base +
          (size_t)(q0 + s * 64 + wave * 16 + c) * 128 + kc * 32 + g * 8);

  const f32x4 fz = {0.f, 0.f, 0.f, 0.f};
  f32x4 o[2][8];
#pragma unroll
  for (int s = 0; s < 2; ++s)
#pragma unroll
    for (int hh = 0; hh < 8; ++hh) o[s][hh] = fz;
  float mrow[2] = {-1e30f, -1e30f};
  float lrow[2] = {0.f, 0.f};

  for (int j = jbeg; j < jend; ++j) {
    lockstep();
    // S^T = K · Q^T, both subs share each K-frag load
    f32x4 s0[4], s1[4];
#pragma unroll
    for (int mt = 0; mt < 4; ++mt) { s0[mt] = fz; s1[mt] = fz; }
#pragma unroll
    for (int kc = 0; kc < 4; ++kc) {
#pragma unroll
      for (int mt = 0; mt < 4; ++mt) {
        f16x8 kf = *(const f16x8*)(kg + base +
            (size_t)(j * 64 + mt * 16 + c) * 128 + kc * 32 + g * 8);
        s0[mt] = __builtin_amdgcn_mfma_f32_16x16x32_f16(kf, qf[0][kc], s0[mt], 0, 0, 0);
        s1[mt] = __builtin_amdgcn_mfma_f32_16x16x32_f16(kf, qf[1][kc], s1[mt], 0, 0, 0);
      }
    }
#pragma unroll
    for (int sub = 0; sub < 2; ++sub) {
      f32x4* s = sub ? s1 : s0;
      int rel = (j - 2 * qt - sub) * 64;   // >=0: masking needed (wave-uniform)
      float tmax = -1e30f;
      if (rel >= 0) {
#pragma unroll
        for (int mt = 0; mt < 4; ++mt)
#pragma unroll
          for (int i = 0; i < 4; ++i) {
            float v = s[mt][i] * SCALE;
            if (rel + mt * 16 + g * 4 + i > wave * 16 + c) v = -1e30f;
            s[mt][i] = v;
            tmax = fmaxf(tmax, v);
          }
      } else {
#pragma unroll
        for (int mt = 0; mt < 4; ++mt)
#pragma unroll
          for (int i = 0; i < 4; ++i) {
            float v = s[mt][i] * SCALE;
            s[mt][i] = v;
            tmax = fmaxf(tmax, v);
          }
      }
      tmax = fmaxf(tmax, __shfl_xor(tmax, 16, 64));
      tmax = fmaxf(tmax, __shfl_xor(tmax, 32, 64));
      float mnew = fmaxf(mrow[sub], tmax);
      float alpha = __builtin_amdgcn_exp2f((mrow[sub] - mnew) * LOG2E);
      float rsum = 0.f;
      float p[4][4];
#pragma unroll
      for (int mt = 0; mt < 4; ++mt)
#pragma unroll
        for (int i = 0; i < 4; ++i) {
          float e = __builtin_amdgcn_exp2f((s[mt][i] - mnew) * LOG2E);
          p[mt][i] = e;
          rsum += e;
        }
      rsum += __shfl_xor(rsum, 16, 64);
      rsum += __shfl_xor(rsum, 32, 64);
      lrow[sub] = lrow[sub] * alpha + rsum;
      mrow[sub] = mnew;
      // alpha: col-world (q=c) -> row-world (q=g*4+i)
      int srcb = (lane & 48) + ((lane & 48) >> 2);
      float ar[4];
#pragma unroll
      for (int i = 0; i < 4; ++i) ar[i] = __shfl(alpha, srcb + i, 64);
#pragma unroll
      for (int hh = 0; hh < 8; ++hh)
#pragma unroll
        for (int i = 0; i < 4; ++i) o[sub][hh][i] *= ar[i];
      // P^T regs -> Ps[q][kv] (per-wave buffer, same-wave dependency only)
#pragma unroll
      for (int mt = 0; mt < 4; ++mt) {
        f16x4 pk;
#pragma unroll
        for (int i = 0; i < 4; ++i) pk[i] = (_Float16)p[mt][i];
        *(f16x4*)(&Ps[wave][sub][0] + c * 72 + mt * 16 + g * 4) = pk;
      }
    }
    // O += P V; V-frags direct from global vT, shared by both subs
#pragma unroll
    for (int kc = 0; kc < 2; ++kc) {
      f16x8 pf0 = *(const f16x8*)(&Ps[wave][0][0] + c * 72 + kc * 32 + g * 8);
      f16x8 pf1 = *(const f16x8*)(&Ps[wave][1][0] + c * 72 + kc * 32 + g * 8);
#pragma unroll
      for (int hh = 0; hh < 8; ++hh) {
        f16x8 vf = *(const f16x8*)(vT + (size_t)(hh * 16 + c) * 16384 +
                                   b * 4096 + j * 64 + kc * 32 + g * 8);
        o[0][hh] = __builtin_amdgcn_mfma_f32_16x16x32_f16(pf0, vf, o[0][hh], 0, 0, 0);
        o[1][hh] = __builtin_amdgcn_mfma_f32_16x16x32_f16(pf1, vf, o[1][hh], 0, 0, 0);
      }
    }
  }
  // write unnormalized partial O + (m,l)
#pragma unroll
  for (int sub = 0; sub < 2; ++sub)
#pragma unroll
    for (int hh = 0; hh < 8; ++hh)
#pragma unroll
      for (int i = 0; i < 4; ++i) {
        int row = sub * 64 + wave * 16 + g * 4 + i;
        Op[(size_t)u * 16384 + row * 128 + hh * 16 + c] = o[sub][hh][i];
      }
  if (lane < 16) {
#pragma unroll
    for (int sub = 0; sub < 2; ++sub) {
      int row = sub * 64 + wave * 16 + lane;
      Ml[(size_t)u * 256 + row * 2]     = mrow[sub];
      Ml[(size_t)u * 256 + row * 2 + 1] = lrow[sub];
    }
  }
}

// ---- merge partials -> out ----
__global__ __launch_bounds__(256) void attn_merge(const float* __restrict__ Op,
    const float* __restrict__ Ml, float* __restrict__ out) {
  int bq = blockIdx.x;
  int b = bq >> 5, qt = bq & 31;
  int nch = qt / 8 + 1;
  int g2 = qt / 8, r = qt % 8;
  int bb = qt + 8 * (g2 * (g2 - 1) / 2) + r * g2;
  int u0 = b * 80 + bb;
  __shared__ float w[4][128];
  int tid = threadIdx.x;
  if (tid < 128) {
    float m[4], l[4];
    float M = -1e30f;
    for (int uu = 0; uu < nch; ++uu) {
      m[uu] = Ml[(size_t)(u0 + uu) * 256 + tid * 2];
      l[uu] = Ml[(size_t)(u0 + uu) * 256 + tid * 2 + 1];
      M = fmaxf(M, m[uu]);
    }
    float L = 0.f;
    for (int uu = 0; uu < nch; ++uu) {
      float e = __builtin_amdgcn_exp2f((m[uu] - M) * LOG2E);
      w[uu][tid] = e;
      L += l[uu] * e;
    }
    float iL = 1.0f / L;
    for (int uu = 0; uu < nch; ++uu) w[uu][tid] *= iL;
  }
  __syncthreads();
  for (int it = 0; it < 64; ++it) {
    int idx = it * 256 + tid;
    int row = idx >> 7;
    float acc = 0.f;
    for (int uu = 0; uu < nch; ++uu)
      acc += w[uu][row] * Op[(size_t)(u0 + uu) * 16384 + idx];
    out[(size_t)b * 4096 * 128 + (size_t)qt * 16384 + idx] = acc;
  }
}

extern "C" void kernel_launch(void* const* d_in, const int* in_sizes, int n_in,
                              void* d_out, int out_size, void* d_ws, size_t ws_size,
                              hipStream_t stream) {
  const float* x  = (const float*)d_in[0];
  const float* Wq = (const float*)d_in[1];
  const float* Wk = (const float*)d_in[2];
  const float* Wv = (const float*)d_in[3];
  const size_t NTOK = (size_t)16384 * 128;
  _Float16* q  = (_Float16*)d_ws;
  _Float16* k  = q + NTOK;
  _Float16* vT = k + NTOK;
  _Float16* Wf = vT + NTOK;                    // 786432 fp16
  float* Op = (float*)(Wf + (size_t)786432);   // 320 * 16384 f32
  float* Ml = Op + (size_t)320 * 16384;        // 320 * 256 f32
  prep_wf<<<384, 256, 0, stream>>>(Wq, Wk, Wv, Wf);
  proj<<<256, 256, 0, stream>>>(x, Wf, q, k, vT);
  attn_part<<<320, 256, 0, stream>>>(q, k, vT, Op, Ml);
  attn_merge<<<128, 256, 0, stream>>>(Op, Ml, (float*)d_out);
}